// Round 5
// baseline (18495.999 us; speedup 1.0000x reference)
//
#include <hip/hip_runtime.h>
#include <stdint.h>

// Problem: B=8, L=4096, D=256, K=4096
#define NROWS 32768
#define KC 4096
#define DIM 256
#define BM 64            // rows per block
#define NCT 128          // col-tiles of 32 codes
#define TPW 32           // col-tiles per wave (4 waves)
#define CAP 40
#define MARGIN 3e-4f     // quant band + 2*bf16 score err + slack (validated R4)

#define OUT_IDX (NROWS * DIM)
#define OUT_SCAL (OUT_IDX + NROWS)

// Workspace layout (bytes)
#define WS_CNORM 0
#define WS_ZNORM 16384
#define WS_LOSS  147456
#define WS_AVGP8 147712                  // 8 shadows x 4096 f32 = 128 KB
#define WS_FRAG  278784                  // bf16 fragment image, 2 MB

typedef __bf16 bf8 __attribute__((ext_vector_type(8)));
typedef float f16v __attribute__((ext_vector_type(16)));

// monotonic float<->uint order maps (argmin with first-index tie-break)
__device__ __forceinline__ unsigned ford(float f) {
  unsigned u = __float_as_uint(f);
  return (u & 0x80000000u) ? ~u : (u | 0x80000000u);
}
__device__ __forceinline__ float unford(unsigned u) {
  return __uint_as_float((u & 0x80000000u) ? (u ^ 0x80000000u) : ~u);
}

// numpy pairwise-sum of x**2 (n=256), bitwise == np.sum(x**2) (validated R2-R4)
__device__ __forceinline__ float np_rownorm256(const float* __restrict__ p) {
  float h[2];
  #pragma unroll
  for (int half = 0; half < 2; ++half) {
    const float* b = p + half * 128;
    float r[8];
    #pragma unroll
    for (int j = 0; j < 8; ++j) { float v = b[j]; r[j] = __fmul_rn(v, v); }
    for (int i = 8; i < 128; i += 8) {
      #pragma unroll
      for (int j = 0; j < 8; ++j) {
        float v = b[i + j];
        r[j] = __fadd_rn(r[j], __fmul_rn(v, v));
      }
    }
    h[half] = __fadd_rn(
        __fadd_rn(__fadd_rn(r[0], r[1]), __fadd_rn(r[2], r[3])),
        __fadd_rn(__fadd_rn(r[4], r[5]), __fadd_rn(r[6], r[7])));
  }
  return __fadd_rn(h[0], h[1]);
}

// cb norms (r<KC) and z norms fused in one launch
__global__ void k_norms(const float* __restrict__ cbw, const float* __restrict__ z,
                        float* __restrict__ cnorm, float* __restrict__ znorm) {
  int r = blockIdx.x * 256 + threadIdx.x;
  if (r < KC) cnorm[r] = np_rownorm256(cbw + (size_t)r * DIM);
  else {
    int q = r - KC;
    if (q < NROWS) znorm[q] = np_rownorm256(z + (size_t)q * DIM);
  }
}

// Build bf16 B-fragment image: frag[ct][ds][lane][8] with
// frag(...)[j] = bf16(cb[ct*32 + (lane&31)][ds*16 + (lane>>5)*8 + j])
__global__ void k_frag(const float* __restrict__ cbw, __bf16* __restrict__ frag) {
  int idx = blockIdx.x * 256 + threadIdx.x;   // 131072 units of 16B
  int c = idx >> 5, u = idx & 31;
  int ds = u >> 1, half = u & 1;
  int ct = c >> 5, m = c & 31;
  int lane = half * 32 + m;
  const float* src = cbw + (size_t)c * DIM + ds * 16 + half * 8;
  float4 a = *(const float4*)src;
  float4 b = *(const float4*)(src + 4);
  bf8 h;
  h[0] = (__bf16)a.x; h[1] = (__bf16)a.y; h[2] = (__bf16)a.z; h[3] = (__bf16)a.w;
  h[4] = (__bf16)b.x; h[5] = (__bf16)b.y; h[6] = (__bf16)b.z; h[7] = (__bf16)b.w;
  *(bf8*)(frag + ((size_t)(ct * 16 + ds) * 64 + lane) * 8) = h;
}

// np-bitwise d2 (validated): sequential fmaf chain, d2 = fl(fl(rn+cn)-fl(2*mm))
__device__ __forceinline__ float exact_d2(const float* __restrict__ zr,
                                          const float* __restrict__ cr,
                                          float rn, float cn) {
  float mm = 0.f;
  for (int d = 0; d < DIM; d += 4) {
    float4 zv = *(const float4*)(zr + d);
    float4 cv = *(const float4*)(cr + d);
    mm = __builtin_fmaf(zv.x, cv.x, mm);
    mm = __builtin_fmaf(zv.y, cv.y, mm);
    mm = __builtin_fmaf(zv.z, cv.z, mm);
    mm = __builtin_fmaf(zv.w, cv.w, mm);
  }
  return __fsub_rn(__fadd_rn(rn, cn), __fmul_rn(2.f, mm));
}

__global__ __launch_bounds__(256, 2) void k_main(
    const float* __restrict__ z, const float* __restrict__ cbw,
    const float* __restrict__ cnorm, const float* __restrict__ znorm,
    const __bf16* __restrict__ frag, float* __restrict__ out,
    float* __restrict__ avgp8, double* __restrict__ losssum) {
  __shared__ __bf16 A1[16 * 64 * 8];               // rows 32..63 frag image, 16 KB
  union CP { int cand[BM][CAP]; float pcol[KC]; }; // phase-disjoint alias
  __shared__ CP cp;
  __shared__ int ccount[BM];
  __shared__ unsigned rowminU[BM];
  __shared__ unsigned long long rowkey[BM];
  __shared__ float esumL[BM], invR[BM], lred[256];
  __shared__ int idxr[BM];

  const int t = threadIdx.x;
  const int lane = t & 63, wv = t >> 6;
  const int ln31 = lane & 31, lh = lane >> 5;
  const int row0 = blockIdx.x * BM;

  if (t < BM) {
    ccount[t] = 0; rowminU[t] = 0xFFFFFFFFu; rowkey[t] = ~0ULL; esumL[t] = 0.f;
  }

  // ---- stage A1 (rows 32..63) frag image into LDS cooperatively ----
  #pragma unroll
  for (int i = 0; i < 4; ++i) {
    int idx = t * 4 + i;              // 1024 units
    int l = idx & 63, ds = idx >> 6;
    int row = 32 + (l & 31), d0 = ds * 16 + (l >> 5) * 8;
    const float* src = z + (size_t)(row0 + row) * DIM + d0;
    float4 a = *(const float4*)src;
    float4 b = *(const float4*)(src + 4);
    bf8 h;
    h[0] = (__bf16)a.x; h[1] = (__bf16)a.y; h[2] = (__bf16)a.z; h[3] = (__bf16)a.w;
    h[4] = (__bf16)b.x; h[5] = (__bf16)b.y; h[6] = (__bf16)b.z; h[7] = (__bf16)b.w;
    *(bf8*)&A1[((size_t)ds * 64 + l) * 8] = h;
  }

  // ---- A0 (rows 0..31) register fragments ----
  bf8 Ah0[16];
  {
    const float* zp = z + (size_t)(row0 + ln31) * DIM + lh * 8;
    #pragma unroll
    for (int ds = 0; ds < 16; ++ds) {
      float4 a = *(const float4*)(zp + ds * 16);
      float4 b = *(const float4*)(zp + ds * 16 + 4);
      bf8 h;
      h[0] = (__bf16)a.x; h[1] = (__bf16)a.y; h[2] = (__bf16)a.z; h[3] = (__bf16)a.w;
      h[4] = (__bf16)b.x; h[5] = (__bf16)b.y; h[6] = (__bf16)b.z; h[7] = (__bf16)b.w;
      Ah0[ds] = h;
    }
  }
  __syncthreads();

  float es[32], rmF[32];
  #pragma unroll
  for (int i = 0; i < 32; ++i) { es[i] = 0.f; rmF[i] = 3.4e38f; }

  // ============ Phase 1: barrier-free streaming sweep ============
  for (int ti = 0; ti < TPW; ++ti) {
    const int ct = wv * TPW + ti;
    const __bf16* tb = frag + (size_t)ct * 8192;
    f16v av[2];
    #pragma unroll
    for (int r = 0; r < 16; ++r) { av[0][r] = 0.f; av[1][r] = 0.f; }
    #pragma unroll
    for (int ds = 0; ds < 16; ++ds) {
      bf8 Bf = *(const bf8*)(tb + (ds * 64 + lane) * 8);
      bf8 A1f = *(const bf8*)&A1[((size_t)ds * 64 + lane) * 8];
      av[0] = __builtin_amdgcn_mfma_f32_32x32x16_bf16(Ah0[ds], Bf, av[0], 0, 0, 0);
      av[1] = __builtin_amdgcn_mfma_f32_32x32x16_bf16(A1f, Bf, av[1], 0, 0, 0);
    }
    const float cn = cnorm[ct * 32 + ln31];
    #pragma unroll
    for (int rg = 0; rg < 2; ++rg) {
      #pragma unroll
      for (int r = 0; r < 16; ++r) {
        const int li = rg * 16 + r;
        const int row = (r & 3) + 8 * (r >> 2) + 4 * lh + 32 * rg;
        float sc = __builtin_fmaf(-2.f, av[rg][r], cn);
        es[li] += __expf(-sc);
        float rm = fminf(rmF[li], unford(rowminU[row]));
        if (sc < rm) { rm = sc; atomicMin(&rowminU[row], ford(sc)); }
        rmF[li] = rm;
        if (sc <= rm + MARGIN) {
          int slot = atomicAdd(&ccount[row], 1);
          if (slot < CAP) cp.cand[row][slot] = ct * 32 + ln31;
        }
      }
    }
  }

  // ---- row exp-sum reduction ----
  #pragma unroll
  for (int li = 0; li < 32; ++li) {
    float e = es[li];
    #pragma unroll
    for (int off = 16; off > 0; off >>= 1) e += __shfl_xor(e, off);
    if (ln31 == 0) {
      int r = li & 15;
      int row = (r & 3) + 8 * (r >> 2) + 4 * lh + 32 * (li >> 4);
      atomicAdd(&esumL[row], e);
    }
  }
  __syncthreads();
  if (t < BM) invR[t] = 1.0f / esumL[t];
  __syncthreads();

  // ---- exact np-bitwise rescore of candidates -> argmin ----
  {
    int r = t & 63, q = t >> 6;   // 4 threads per row
    int cnt = ccount[r];
    const float* zr = z + (size_t)(row0 + r) * DIM;
    float rn = znorm[row0 + r];
    if (cnt <= CAP) {
      for (int s = q; s < cnt; s += 4) {
        int k = cp.cand[r][s];
        float d2 = exact_d2(zr, cbw + (size_t)k * DIM, rn, cnorm[k]);
        atomicMin(&rowkey[r], (((unsigned long long)ford(d2)) << 32) | (unsigned)k);
      }
    } else {  // overflow (improbable): full exact scan, still correct
      for (int k = q; k < KC; k += 4) {
        float d2 = exact_d2(zr, cbw + (size_t)k * DIM, rn, cnorm[k]);
        atomicMin(&rowkey[r], (((unsigned long long)ford(d2)) << 32) | (unsigned)k);
      }
    }
  }
  __syncthreads();
  if (t < BM) {
    int idx = (int)(rowkey[t] & 0xFFFFFFFFULL);
    idxr[t] = idx;
    out[OUT_IDX + row0 + t] = (float)idx;
  }
  __syncthreads();

  // ---- z_q gather, STE output, loss partial ----
  float lacc = 0.f;
  for (int r = 0; r < BM; ++r) {
    int idx = idxr[r];
    float zq = cbw[(size_t)idx * DIM + t];
    float zv = z[(size_t)(row0 + r) * DIM + t];
    float df = __fsub_rn(zq, zv);
    out[(size_t)(row0 + r) * DIM + t] = __fadd_rn(zv, df);
    lacc += df * df;
  }
  lred[t] = lacc;
  __syncthreads();
  #pragma unroll
  for (int s = 128; s > 0; s >>= 1) {
    if (t < s) lred[t] += lred[t + s];
    __syncthreads();
  }
  if (t == 0) atomicAdd(losssum, (double)lred[0]);
  __syncthreads();   // cand no longer needed; pcol alias safe beyond here

  // ============ Phase 2: barrier-free avg_probs sweep ============
  for (int ti = 0; ti < TPW; ++ti) {
    const int ct = wv * TPW + ti;
    const __bf16* tb = frag + (size_t)ct * 8192;
    f16v av[2];
    #pragma unroll
    for (int r = 0; r < 16; ++r) { av[0][r] = 0.f; av[1][r] = 0.f; }
    #pragma unroll
    for (int ds = 0; ds < 16; ++ds) {
      bf8 Bf = *(const bf8*)(tb + (ds * 64 + lane) * 8);
      bf8 A1f = *(const bf8*)&A1[((size_t)ds * 64 + lane) * 8];
      av[0] = __builtin_amdgcn_mfma_f32_32x32x16_bf16(Ah0[ds], Bf, av[0], 0, 0, 0);
      av[1] = __builtin_amdgcn_mfma_f32_32x32x16_bf16(A1f, Bf, av[1], 0, 0, 0);
    }
    const float cn = cnorm[ct * 32 + ln31];
    float s = 0.f;
    #pragma unroll
    for (int rg = 0; rg < 2; ++rg) {
      #pragma unroll
      for (int r = 0; r < 16; ++r) {
        const int row = (r & 3) + 8 * (r >> 2) + 4 * lh + 32 * rg;
        float sc = __builtin_fmaf(-2.f, av[rg][r], cn);
        s += __expf(-sc) * invR[row];
      }
    }
    s += __shfl_xor(s, 32);           // merge the two lh halves (same col)
    if (lh == 0) cp.pcol[ct * 32 + ln31] = s;  // unique writer per col
  }
  __syncthreads();
  {
    float* shadow = avgp8 + (size_t)(blockIdx.x & 7) * KC;
    #pragma unroll
    for (int i = 0; i < 16; ++i)
      atomicAdd(&shadow[t + 256 * i], cp.pcol[t + 256 * i]);
  }
}

__global__ void k_final(const float* __restrict__ avgp8,
                        const double* __restrict__ losssum,
                        float* __restrict__ out) {
  const int t = threadIdx.x;
  double part = 0.0;
  for (int k = t; k < KC; k += 256) {
    float a4 = 0.f;
    #pragma unroll
    for (int s = 0; s < 8; ++s) a4 += avgp8[s * KC + k];
    double a = (double)a4 / (double)NROWS;
    part += a * log(a + 1e-10);
  }
  __shared__ double sd[256];
  sd[t] = part;
  __syncthreads();
  for (int s = 128; s > 0; s >>= 1) {
    if (t < s) sd[t] += sd[t + s];
    __syncthreads();
  }
  if (t == 0) {
    double H = -sd[0];
    double mse = losssum[0] / (double)((size_t)NROWS * DIM);
    double ccl = 1.25 * mse;
    double sel = -0.1 * H;
    out[OUT_SCAL + 0] = (float)(ccl + sel);
    out[OUT_SCAL + 1] = (float)ccl;
    out[OUT_SCAL + 2] = (float)sel;
  }
}

extern "C" void kernel_launch(void* const* d_in, const int* in_sizes, int n_in,
                              void* d_out, int out_size, void* d_ws, size_t ws_size,
                              hipStream_t stream) {
  const float* z = (const float*)d_in[0];
  const float* cbw = (const float*)d_in[1];
  float* out = (float*)d_out;
  char* ws = (char*)d_ws;
  float* cnorm = (float*)(ws + WS_CNORM);
  float* znorm = (float*)(ws + WS_ZNORM);
  double* losssum = (double*)(ws + WS_LOSS);
  float* avgp8 = (float*)(ws + WS_AVGP8);
  __bf16* frag = (__bf16*)(ws + WS_FRAG);

  hipMemsetAsync(ws + WS_LOSS, 0, 8, stream);
  hipMemsetAsync(ws + WS_AVGP8, 0, 8 * KC * 4, stream);
  k_norms<<<(KC + NROWS) / 256, 256, 0, stream>>>(cbw, z, cnorm, znorm);
  k_frag<<<(KC * 32) / 256, 256, 0, stream>>>(cbw, frag);
  k_main<<<NROWS / BM, 256, 0, stream>>>(z, cbw, cnorm, znorm, frag, out,
                                         avgp8, losssum);
  k_final<<<1, 256, 0, stream>>>(avgp8, losssum, out);
}

// Round 6
// 501.663 us; speedup vs baseline: 36.8694x; 36.8694x over previous
//
#include <hip/hip_runtime.h>
#include <stdint.h>

// Problem: B=8, L=4096, D=256, K=4096
#define NROWS 32768
#define KC 4096
#define DIM 256
#define BM 64            // rows per block
#define NCT 128          // col-tiles of 32 codes
#define TPW 32           // col-tiles per wave (4 waves)
#define CAP 40
#define MARGIN 3e-4f     // quant band + 2*bf16 score err + slack (validated R4)

#define OUT_IDX (NROWS * DIM)
#define OUT_SCAL (OUT_IDX + NROWS)

// Workspace layout (bytes)
#define WS_CNORM 0
#define WS_ZNORM 16384
#define WS_LOSS  147456
#define WS_AVGP8 147712                  // 8 shadows x 4096 f32 = 128 KB
#define WS_FRAG  278784                  // bf16 fragment image, 2 MB

typedef __bf16 bf8 __attribute__((ext_vector_type(8)));
typedef float f16v __attribute__((ext_vector_type(16)));

// monotonic float<->uint order maps (argmin with first-index tie-break)
__device__ __forceinline__ unsigned ford(float f) {
  unsigned u = __float_as_uint(f);
  return (u & 0x80000000u) ? ~u : (u | 0x80000000u);
}
__device__ __forceinline__ float unford(unsigned u) {
  return __uint_as_float((u & 0x80000000u) ? (u ^ 0x80000000u) : ~u);
}

// numpy pairwise-sum of x**2 (n=256), bitwise == np.sum(x**2) (validated R2-R4)
__device__ __forceinline__ float np_rownorm256(const float* __restrict__ p) {
  float h[2];
  #pragma unroll
  for (int half = 0; half < 2; ++half) {
    const float* b = p + half * 128;
    float r[8];
    #pragma unroll
    for (int j = 0; j < 8; ++j) { float v = b[j]; r[j] = __fmul_rn(v, v); }
    for (int i = 8; i < 128; i += 8) {
      #pragma unroll
      for (int j = 0; j < 8; ++j) {
        float v = b[i + j];
        r[j] = __fadd_rn(r[j], __fmul_rn(v, v));
      }
    }
    h[half] = __fadd_rn(
        __fadd_rn(__fadd_rn(r[0], r[1]), __fadd_rn(r[2], r[3])),
        __fadd_rn(__fadd_rn(r[4], r[5]), __fadd_rn(r[6], r[7])));
  }
  return __fadd_rn(h[0], h[1]);
}

// cb norms (r<KC) and z norms fused in one launch
__global__ void k_norms(const float* __restrict__ cbw, const float* __restrict__ z,
                        float* __restrict__ cnorm, float* __restrict__ znorm) {
  int r = blockIdx.x * 256 + threadIdx.x;
  if (r < KC) cnorm[r] = np_rownorm256(cbw + (size_t)r * DIM);
  else {
    int q = r - KC;
    if (q < NROWS) znorm[q] = np_rownorm256(z + (size_t)q * DIM);
  }
}

// Build bf16 B-fragment image: frag[ct][ds][lane][8] with
// frag(...)[j] = bf16(cb[ct*32 + (lane&31)][ds*16 + (lane>>5)*8 + j])
__global__ void k_frag(const float* __restrict__ cbw, __bf16* __restrict__ frag) {
  int idx = blockIdx.x * 256 + threadIdx.x;   // 131072 units of 16B
  int c = idx >> 5, u = idx & 31;
  int ds = u >> 1, half = u & 1;
  int ct = c >> 5, m = c & 31;
  int lane = half * 32 + m;
  const float* src = cbw + (size_t)c * DIM + ds * 16 + half * 8;
  float4 a = *(const float4*)src;
  float4 b = *(const float4*)(src + 4);
  bf8 h;
  h[0] = (__bf16)a.x; h[1] = (__bf16)a.y; h[2] = (__bf16)a.z; h[3] = (__bf16)a.w;
  h[4] = (__bf16)b.x; h[5] = (__bf16)b.y; h[6] = (__bf16)b.z; h[7] = (__bf16)b.w;
  *(bf8*)(frag + ((size_t)(ct * 16 + ds) * 64 + lane) * 8) = h;
}

// np-bitwise d2 (validated): sequential fmaf chain, d2 = fl(fl(rn+cn)-fl(2*mm))
__device__ __forceinline__ float exact_d2(const float* __restrict__ zr,
                                          const float* __restrict__ cr,
                                          float rn, float cn) {
  float mm = 0.f;
  for (int d = 0; d < DIM; d += 4) {
    float4 zv = *(const float4*)(zr + d);
    float4 cv = *(const float4*)(cr + d);
    mm = __builtin_fmaf(zv.x, cv.x, mm);
    mm = __builtin_fmaf(zv.y, cv.y, mm);
    mm = __builtin_fmaf(zv.z, cv.z, mm);
    mm = __builtin_fmaf(zv.w, cv.w, mm);
  }
  return __fsub_rn(__fadd_rn(rn, cn), __fmul_rn(2.f, mm));
}

// one 64x32 score tile: A0 (regs) + A1 (LDS) vs B tile streamed from frag
__device__ __forceinline__ void tile_mfma(const bf8* __restrict__ Ah0,
                                          const __bf16* __restrict__ A1,
                                          const __bf16* __restrict__ tb,
                                          int lane, f16v av[2]) {
  #pragma unroll
  for (int r = 0; r < 16; ++r) { av[0][r] = 0.f; av[1][r] = 0.f; }
  #pragma unroll
  for (int ds = 0; ds < 16; ++ds) {
    bf8 Bf = *(const bf8*)(tb + (ds * 64 + lane) * 8);
    bf8 A1f = *(const bf8*)&A1[((size_t)ds * 64 + lane) * 8];
    av[0] = __builtin_amdgcn_mfma_f32_32x32x16_bf16(Ah0[ds], Bf, av[0], 0, 0, 0);
    av[1] = __builtin_amdgcn_mfma_f32_32x32x16_bf16(A1f, Bf, av[1], 0, 0, 0);
  }
}

__global__ __launch_bounds__(256, 2) void k_main(
    const float* __restrict__ z, const float* __restrict__ cbw,
    const float* __restrict__ cnorm, const float* __restrict__ znorm,
    const __bf16* __restrict__ frag, float* __restrict__ out,
    float* __restrict__ avgp8, double* __restrict__ losssum) {
  __shared__ __bf16 A1[16 * 64 * 8];               // rows 32..63 frag image, 16 KB
  union CP { int cand[BM][CAP]; float pcol[KC]; }; // phase-disjoint alias
  __shared__ CP cp;
  __shared__ int ccount[BM];
  __shared__ unsigned rowminU[BM];
  __shared__ unsigned long long rowkey[BM];
  __shared__ float esumL[BM], invR[BM], lred[256];
  __shared__ int idxr[BM];

  const int t = threadIdx.x;
  const int lane = t & 63, wv = t >> 6;
  const int ln31 = lane & 31, lh = lane >> 5;
  const int row0 = blockIdx.x * BM;

  if (t < BM) {
    ccount[t] = 0; rowminU[t] = 0xFFFFFFFFu; rowkey[t] = ~0ULL; esumL[t] = 0.f;
  }

  // ---- stage A1 (rows 32..63) frag image into LDS cooperatively ----
  #pragma unroll
  for (int i = 0; i < 4; ++i) {
    int idx = t * 4 + i;              // 1024 units
    int l = idx & 63, ds = idx >> 6;
    int row = 32 + (l & 31), d0 = ds * 16 + (l >> 5) * 8;
    const float* src = z + (size_t)(row0 + row) * DIM + d0;
    float4 a = *(const float4*)src;
    float4 b = *(const float4*)(src + 4);
    bf8 h;
    h[0] = (__bf16)a.x; h[1] = (__bf16)a.y; h[2] = (__bf16)a.z; h[3] = (__bf16)a.w;
    h[4] = (__bf16)b.x; h[5] = (__bf16)b.y; h[6] = (__bf16)b.z; h[7] = (__bf16)b.w;
    *(bf8*)&A1[((size_t)ds * 64 + l) * 8] = h;
  }

  // ---- A0 (rows 0..31) register fragments ----
  bf8 Ah0[16];
  {
    const float* zp = z + (size_t)(row0 + ln31) * DIM + lh * 8;
    #pragma unroll
    for (int ds = 0; ds < 16; ++ds) {
      float4 a = *(const float4*)(zp + ds * 16);
      float4 b = *(const float4*)(zp + ds * 16 + 4);
      bf8 h;
      h[0] = (__bf16)a.x; h[1] = (__bf16)a.y; h[2] = (__bf16)a.z; h[3] = (__bf16)a.w;
      h[4] = (__bf16)b.x; h[5] = (__bf16)b.y; h[6] = (__bf16)b.z; h[7] = (__bf16)b.w;
      Ah0[ds] = h;
    }
  }
  __syncthreads();

  // ---- PRIME rowminU: each wave scores its first tile, min only, no insert.
  // (R5 lacked this -> CAP overflow on every row -> full-scan fallback, 18ms.)
  {
    const int ct = wv * TPW;
    f16v av[2];
    tile_mfma(Ah0, A1, frag + (size_t)ct * 8192, lane, av);
    const float cn = cnorm[ct * 32 + ln31];
    #pragma unroll
    for (int rg = 0; rg < 2; ++rg) {
      #pragma unroll
      for (int r = 0; r < 16; ++r) {
        const int row = (r & 3) + 8 * (r >> 2) + 4 * lh + 32 * rg;
        float sc = __builtin_fmaf(-2.f, av[rg][r], cn);
        atomicMin(&rowminU[row], ford(sc));
      }
    }
  }
  __syncthreads();

  float es[32], rmF[32];
  #pragma unroll
  for (int i = 0; i < 32; ++i) { es[i] = 0.f; rmF[i] = 3.4e38f; }

  // ============ Phase 1: barrier-free streaming sweep ============
  for (int ti = 0; ti < TPW; ++ti) {
    const int ct = wv * TPW + ti;
    f16v av[2];
    tile_mfma(Ah0, A1, frag + (size_t)ct * 8192, lane, av);
    const float cn = cnorm[ct * 32 + ln31];
    #pragma unroll
    for (int rg = 0; rg < 2; ++rg) {
      #pragma unroll
      for (int r = 0; r < 16; ++r) {
        const int li = rg * 16 + r;
        const int row = (r & 3) + 8 * (r >> 2) + 4 * lh + 32 * rg;
        float sc = __builtin_fmaf(-2.f, av[rg][r], cn);
        es[li] += __expf(-sc);
        float rm = fminf(rmF[li], unford(rowminU[row]));
        if (sc < rm) { rm = sc; atomicMin(&rowminU[row], ford(sc)); }
        rmF[li] = rm;
        if (sc <= rm + MARGIN) {
          int slot = atomicAdd(&ccount[row], 1);
          if (slot < CAP) cp.cand[row][slot] = ct * 32 + ln31;
        }
      }
    }
  }

  // ---- row exp-sum reduction ----
  #pragma unroll
  for (int li = 0; li < 32; ++li) {
    float e = es[li];
    #pragma unroll
    for (int off = 16; off > 0; off >>= 1) e += __shfl_xor(e, off);
    if (ln31 == 0) {
      int r = li & 15;
      int row = (r & 3) + 8 * (r >> 2) + 4 * lh + 32 * (li >> 4);
      atomicAdd(&esumL[row], e);
    }
  }
  __syncthreads();
  if (t < BM) invR[t] = 1.0f / esumL[t];
  __syncthreads();

  // ---- exact np-bitwise rescore of candidates -> argmin ----
  {
    int r = t & 63, q = t >> 6;   // 4 threads per row
    int cnt = ccount[r];
    const float* zr = z + (size_t)(row0 + r) * DIM;
    float rn = znorm[row0 + r];
    if (cnt <= CAP) {
      for (int s = q; s < cnt; s += 4) {
        int k = cp.cand[r][s];
        float d2 = exact_d2(zr, cbw + (size_t)k * DIM, rn, cnorm[k]);
        atomicMin(&rowkey[r], (((unsigned long long)ford(d2)) << 32) | (unsigned)k);
      }
    } else {  // overflow (improbable): full exact scan, still correct
      for (int k = q; k < KC; k += 4) {
        float d2 = exact_d2(zr, cbw + (size_t)k * DIM, rn, cnorm[k]);
        atomicMin(&rowkey[r], (((unsigned long long)ford(d2)) << 32) | (unsigned)k);
      }
    }
  }
  __syncthreads();
  if (t < BM) {
    int idx = (int)(rowkey[t] & 0xFFFFFFFFULL);
    idxr[t] = idx;
    out[OUT_IDX + row0 + t] = (float)idx;
  }
  __syncthreads();

  // ---- z_q gather, STE output, loss partial ----
  float lacc = 0.f;
  for (int r = 0; r < BM; ++r) {
    int idx = idxr[r];
    float zq = cbw[(size_t)idx * DIM + t];
    float zv = z[(size_t)(row0 + r) * DIM + t];
    float df = __fsub_rn(zq, zv);
    out[(size_t)(row0 + r) * DIM + t] = __fadd_rn(zv, df);
    lacc += df * df;
  }
  lred[t] = lacc;
  __syncthreads();
  #pragma unroll
  for (int s = 128; s > 0; s >>= 1) {
    if (t < s) lred[t] += lred[t + s];
    __syncthreads();
  }
  if (t == 0) atomicAdd(losssum, (double)lred[0]);
  __syncthreads();   // cand no longer needed; pcol alias safe beyond here

  // ============ Phase 2: barrier-free avg_probs sweep ============
  for (int ti = 0; ti < TPW; ++ti) {
    const int ct = wv * TPW + ti;
    f16v av[2];
    tile_mfma(Ah0, A1, frag + (size_t)ct * 8192, lane, av);
    const float cn = cnorm[ct * 32 + ln31];
    float s = 0.f;
    #pragma unroll
    for (int rg = 0; rg < 2; ++rg) {
      #pragma unroll
      for (int r = 0; r < 16; ++r) {
        const int row = (r & 3) + 8 * (r >> 2) + 4 * lh + 32 * rg;
        float sc = __builtin_fmaf(-2.f, av[rg][r], cn);
        s += __expf(-sc) * invR[row];
      }
    }
    s += __shfl_xor(s, 32);           // merge the two lh halves (same col)
    if (lh == 0) cp.pcol[ct * 32 + ln31] = s;  // unique writer per col
  }
  __syncthreads();
  {
    float* shadow = avgp8 + (size_t)(blockIdx.x & 7) * KC;
    #pragma unroll
    for (int i = 0; i < 16; ++i)
      atomicAdd(&shadow[t + 256 * i], cp.pcol[t + 256 * i]);
  }
}

__global__ void k_final(const float* __restrict__ avgp8,
                        const double* __restrict__ losssum,
                        float* __restrict__ out) {
  const int t = threadIdx.x;
  double part = 0.0;
  for (int k = t; k < KC; k += 256) {
    float a4 = 0.f;
    #pragma unroll
    for (int s = 0; s < 8; ++s) a4 += avgp8[s * KC + k];
    double a = (double)a4 / (double)NROWS;
    part += a * log(a + 1e-10);
  }
  __shared__ double sd[256];
  sd[t] = part;
  __syncthreads();
  for (int s = 128; s > 0; s >>= 1) {
    if (t < s) sd[t] += sd[t + s];
    __syncthreads();
  }
  if (t == 0) {
    double H = -sd[0];
    double mse = losssum[0] / (double)((size_t)NROWS * DIM);
    double ccl = 1.25 * mse;
    double sel = -0.1 * H;
    out[OUT_SCAL + 0] = (float)(ccl + sel);
    out[OUT_SCAL + 1] = (float)ccl;
    out[OUT_SCAL + 2] = (float)sel;
  }
}

extern "C" void kernel_launch(void* const* d_in, const int* in_sizes, int n_in,
                              void* d_out, int out_size, void* d_ws, size_t ws_size,
                              hipStream_t stream) {
  const float* z = (const float*)d_in[0];
  const float* cbw = (const float*)d_in[1];
  float* out = (float*)d_out;
  char* ws = (char*)d_ws;
  float* cnorm = (float*)(ws + WS_CNORM);
  float* znorm = (float*)(ws + WS_ZNORM);
  double* losssum = (double*)(ws + WS_LOSS);
  float* avgp8 = (float*)(ws + WS_AVGP8);
  __bf16* frag = (__bf16*)(ws + WS_FRAG);

  hipMemsetAsync(ws + WS_LOSS, 0, 8, stream);
  hipMemsetAsync(ws + WS_AVGP8, 0, 8 * KC * 4, stream);
  k_norms<<<(KC + NROWS) / 256, 256, 0, stream>>>(cbw, z, cnorm, znorm);
  k_frag<<<(KC * 32) / 256, 256, 0, stream>>>(cbw, frag);
  k_main<<<NROWS / BM, 256, 0, stream>>>(z, cbw, cnorm, znorm, frag, out,
                                         avgp8, losssum);
  k_final<<<1, 256, 0, stream>>>(avgp8, losssum, out);
}

// Round 7
// 477.055 us; speedup vs baseline: 38.7712x; 1.0516x over previous
//
#include <hip/hip_runtime.h>
#include <stdint.h>

// Problem: B=8, L=4096, D=256, K=4096
#define NROWS 32768
#define KC 4096
#define DIM 256
#define BM 32            // rows per block
#define NCT 128          // col-tiles of 32 codes
#define TPW 32           // col-tiles per wave (4 waves)
#define CAP 40
#define KAPPA 0.99960f   // exp(-margin), margin 4e-4 > validated 3e-4
#define K2L2E 2.88539008f // 2*log2(e)
#define L2E 1.44269504f

#define OUT_IDX (NROWS * DIM)
#define OUT_SCAL (OUT_IDX + NROWS)

// Workspace layout (bytes)
#define WS_CNORM 0
#define WS_ZNORM 16384
#define WS_LOSS  147456
#define WS_AVGP8 147712                  // 8 shadows x 4096 f32 = 128 KB
#define WS_FRAG  278784                  // bf16 fragment image, 2 MB

typedef __bf16 bf8 __attribute__((ext_vector_type(8)));
typedef float f16v __attribute__((ext_vector_type(16)));

// monotonic float->uint order map (argmin with first-index tie-break)
__device__ __forceinline__ unsigned ford(float f) {
  unsigned u = __float_as_uint(f);
  return (u & 0x80000000u) ? ~u : (u | 0x80000000u);
}

// numpy pairwise-sum of x**2 (n=256), bitwise == np.sum(x**2) (validated R2-R6)
__device__ __forceinline__ float np_rownorm256(const float* __restrict__ p) {
  float h[2];
  #pragma unroll
  for (int half = 0; half < 2; ++half) {
    const float* b = p + half * 128;
    float r[8];
    #pragma unroll
    for (int j = 0; j < 8; ++j) { float v = b[j]; r[j] = __fmul_rn(v, v); }
    for (int i = 8; i < 128; i += 8) {
      #pragma unroll
      for (int j = 0; j < 8; ++j) {
        float v = b[i + j];
        r[j] = __fadd_rn(r[j], __fmul_rn(v, v));
      }
    }
    h[half] = __fadd_rn(
        __fadd_rn(__fadd_rn(r[0], r[1]), __fadd_rn(r[2], r[3])),
        __fadd_rn(__fadd_rn(r[4], r[5]), __fadd_rn(r[6], r[7])));
  }
  return __fadd_rn(h[0], h[1]);
}

__global__ void k_norms(const float* __restrict__ cbw, const float* __restrict__ z,
                        float* __restrict__ cnorm, float* __restrict__ znorm) {
  int r = blockIdx.x * 256 + threadIdx.x;
  if (r < KC) cnorm[r] = np_rownorm256(cbw + (size_t)r * DIM);
  else {
    int q = r - KC;
    if (q < NROWS) znorm[q] = np_rownorm256(z + (size_t)q * DIM);
  }
}

// Build bf16 B-fragment image: frag[ct][ds][lane][8] with
// frag(...)[j] = bf16(cb[ct*32 + (lane&31)][ds*16 + (lane>>5)*8 + j])
__global__ void k_frag(const float* __restrict__ cbw, __bf16* __restrict__ frag) {
  int idx = blockIdx.x * 256 + threadIdx.x;   // 131072 units of 16B
  int c = idx >> 5, u = idx & 31;
  int ds = u >> 1, half = u & 1;
  int ct = c >> 5, m = c & 31;
  int lane = half * 32 + m;
  const float* src = cbw + (size_t)c * DIM + ds * 16 + half * 8;
  float4 a = *(const float4*)src;
  float4 b = *(const float4*)(src + 4);
  bf8 h;
  h[0] = (__bf16)a.x; h[1] = (__bf16)a.y; h[2] = (__bf16)a.z; h[3] = (__bf16)a.w;
  h[4] = (__bf16)b.x; h[5] = (__bf16)b.y; h[6] = (__bf16)b.z; h[7] = (__bf16)b.w;
  *(bf8*)(frag + ((size_t)(ct * 16 + ds) * 64 + lane) * 8) = h;
}

// np-bitwise d2 (validated): sequential fmaf chain, d2 = fl(fl(rn+cn)-fl(2*mm))
__device__ __forceinline__ float exact_d2(const float* __restrict__ zr,
                                          const float* __restrict__ cr,
                                          float rn, float cn) {
  float mm = 0.f;
  for (int d = 0; d < DIM; d += 4) {
    float4 zv = *(const float4*)(zr + d);
    float4 cv = *(const float4*)(cr + d);
    mm = __builtin_fmaf(zv.x, cv.x, mm);
    mm = __builtin_fmaf(zv.y, cv.y, mm);
    mm = __builtin_fmaf(zv.z, cv.z, mm);
    mm = __builtin_fmaf(zv.w, cv.w, mm);
  }
  return __fsub_rn(__fadd_rn(rn, cn), __fmul_rn(2.f, mm));
}

// one 32x32 score tile: A (LDS frag image) x B (global frag stream)
__device__ __forceinline__ void tile_mfma(const __bf16* __restrict__ Aimg,
                                          const __bf16* __restrict__ tb,
                                          int lane, f16v& acc) {
  #pragma unroll
  for (int r = 0; r < 16; ++r) acc[r] = 0.f;
  #pragma unroll
  for (int ds = 0; ds < 16; ++ds) {
    bf8 Bf = *(const bf8*)(tb + (ds * 64 + lane) * 8);
    bf8 Af = *(const bf8*)&Aimg[((size_t)ds * 64 + lane) * 8];
    acc = __builtin_amdgcn_mfma_f32_32x32x16_bf16(Af, Bf, acc, 0, 0, 0);
  }
}

__global__ __launch_bounds__(256, 4) void k_main(
    const float* __restrict__ z, const float* __restrict__ cbw,
    const float* __restrict__ cnorm, const float* __restrict__ znorm,
    const __bf16* __restrict__ frag, float* __restrict__ out,
    float* __restrict__ avgp8, double* __restrict__ losssum) {
  __shared__ __bf16 Aimg[16 * 64 * 8];             // 32-row frag image, 16 KB
  union CP { int cand[BM][CAP]; float pcol[KC]; }; // phase-disjoint alias
  __shared__ CP cp;
  __shared__ int ccount[BM];
  __shared__ unsigned rowmaxU[BM];                 // running max of e (exp domain)
  __shared__ unsigned long long rowkey[BM];
  __shared__ float esumL[BM], invR[BM], lred[256];
  __shared__ int idxr[BM];

  const int t = threadIdx.x;
  const int lane = t & 63, wv = t >> 6;
  const int ln31 = lane & 31, lh = lane >> 5;
  const int row0 = blockIdx.x * BM;

  if (t < BM) {
    ccount[t] = 0; rowmaxU[t] = 0u; rowkey[t] = ~0ULL; esumL[t] = 0.f;
  }

  // ---- stage A (rows 0..31) frag image into LDS cooperatively ----
  #pragma unroll
  for (int i = 0; i < 4; ++i) {
    int idx = t * 4 + i;              // 1024 units of 16B
    int l = idx & 63, ds = idx >> 6;
    int row = l & 31, d0 = ds * 16 + (l >> 5) * 8;
    const float* src = z + (size_t)(row0 + row) * DIM + d0;
    float4 a = *(const float4*)src;
    float4 b = *(const float4*)(src + 4);
    bf8 h;
    h[0] = (__bf16)a.x; h[1] = (__bf16)a.y; h[2] = (__bf16)a.z; h[3] = (__bf16)a.w;
    h[4] = (__bf16)b.x; h[5] = (__bf16)b.y; h[6] = (__bf16)b.z; h[7] = (__bf16)b.w;
    *(bf8*)&Aimg[((size_t)ds * 64 + l) * 8] = h;
  }
  __syncthreads();

  // ---- PRIME rowmaxU: each wave scores its first tile (max only, no insert)
  {
    const int ct = wv * TPW;
    f16v acc;
    tile_mfma(Aimg, frag + (size_t)ct * 8192, lane, acc);
    const float cnl = cnorm[ct * 32 + ln31] * L2E;
    #pragma unroll
    for (int r = 0; r < 16; ++r) {
      const int row = (r & 3) + 8 * (r >> 2) + 4 * lh;
      float e = exp2f(__builtin_fmaf(acc[r], K2L2E, -cnl));
      atomicMax(&rowmaxU[row], __float_as_uint(e));  // e>0: bits order-preserving
    }
  }
  __syncthreads();

  float es[16], em[16];
  #pragma unroll
  for (int i = 0; i < 16; ++i) { es[i] = 0.f; em[i] = 0.f; }

  // ============ Phase 1: barrier-free streaming sweep (exp domain) ============
  for (int ti = 0; ti < TPW; ++ti) {
    const int ct = wv * TPW + ti;
    f16v acc;
    tile_mfma(Aimg, frag + (size_t)ct * 8192, lane, acc);
    const float cnl = cnorm[ct * 32 + ln31] * L2E;
    #pragma unroll
    for (int r = 0; r < 16; ++r) {
      const int row = (r & 3) + 8 * (r >> 2) + 4 * lh;
      float e = exp2f(__builtin_fmaf(acc[r], K2L2E, -cnl));
      es[r] += e;
      float rm = fmaxf(em[r], __uint_as_float(rowmaxU[row]));  // shared running max
      if (e > rm) { atomicMax(&rowmaxU[row], __float_as_uint(e)); rm = e; }
      em[r] = rm;
      if (e >= rm * KAPPA) {  // within margin of current best -> candidate
        int slot = atomicAdd(&ccount[row], 1);
        if (slot < CAP) cp.cand[row][slot] = ct * 32 + ln31;
      }
    }
  }

  // ---- row exp-sum reduction (32 lanes of same half share rows) ----
  #pragma unroll
  for (int r = 0; r < 16; ++r) {
    float e = es[r];
    #pragma unroll
    for (int off = 16; off > 0; off >>= 1) e += __shfl_xor(e, off);
    if (ln31 == 0) {
      const int row = (r & 3) + 8 * (r >> 2) + 4 * lh;
      atomicAdd(&esumL[row], e);
    }
  }
  __syncthreads();
  if (t < BM) invR[t] = 1.0f / esumL[t];
  __syncthreads();

  // ---- exact np-bitwise rescore of candidates -> argmin ----
  {
    int r = t & 31, q = t >> 5;   // 8 threads per row
    int cnt = ccount[r];
    const float* zr = z + (size_t)(row0 + r) * DIM;
    float rn = znorm[row0 + r];
    if (cnt <= CAP) {
      for (int s = q; s < cnt; s += 8) {
        int k = cp.cand[r][s];
        float d2 = exact_d2(zr, cbw + (size_t)k * DIM, rn, cnorm[k]);
        atomicMin(&rowkey[r], (((unsigned long long)ford(d2)) << 32) | (unsigned)k);
      }
    } else {  // overflow (improbable): full exact scan, still correct
      for (int k = q; k < KC; k += 8) {
        float d2 = exact_d2(zr, cbw + (size_t)k * DIM, rn, cnorm[k]);
        atomicMin(&rowkey[r], (((unsigned long long)ford(d2)) << 32) | (unsigned)k);
      }
    }
  }
  __syncthreads();
  if (t < BM) {
    int idx = (int)(rowkey[t] & 0xFFFFFFFFULL);
    idxr[t] = idx;
    out[OUT_IDX + row0 + t] = (float)idx;
  }
  __syncthreads();

  // ---- z_q gather, STE output, loss partial ----
  float lacc = 0.f;
  for (int r = 0; r < BM; ++r) {
    int idx = idxr[r];
    float zq = cbw[(size_t)idx * DIM + t];
    float zv = z[(size_t)(row0 + r) * DIM + t];
    float df = __fsub_rn(zq, zv);
    out[(size_t)(row0 + r) * DIM + t] = __fadd_rn(zv, df);
    lacc += df * df;
  }
  lred[t] = lacc;
  __syncthreads();
  #pragma unroll
  for (int s = 128; s > 0; s >>= 1) {
    if (t < s) lred[t] += lred[t + s];
    __syncthreads();
  }
  if (t == 0) atomicAdd(losssum, (double)lred[0]);

  // ---- invR to regs for phase 2 ----
  float ir[16];
  #pragma unroll
  for (int r = 0; r < 16; ++r)
    ir[r] = invR[(r & 3) + 8 * (r >> 2) + 4 * lh];
  __syncthreads();   // cand dead; pcol alias safe beyond here

  // ============ Phase 2: barrier-free avg_probs sweep ============
  for (int ti = 0; ti < TPW; ++ti) {
    const int ct = wv * TPW + ti;
    f16v acc;
    tile_mfma(Aimg, frag + (size_t)ct * 8192, lane, acc);
    const float cnl = cnorm[ct * 32 + ln31] * L2E;
    float s = 0.f;
    #pragma unroll
    for (int r = 0; r < 16; ++r) {
      float e = exp2f(__builtin_fmaf(acc[r], K2L2E, -cnl));
      s = __builtin_fmaf(e, ir[r], s);
    }
    s += __shfl_xor(s, 32);           // merge the two lh halves (same col)
    if (lh == 0) cp.pcol[ct * 32 + ln31] = s;  // unique writer per col
  }
  __syncthreads();
  {
    float* shadow = avgp8 + (size_t)(blockIdx.x & 7) * KC;
    #pragma unroll
    for (int i = 0; i < 16; ++i)
      atomicAdd(&shadow[t + 256 * i], cp.pcol[t + 256 * i]);
  }
}

__global__ void k_final(const float* __restrict__ avgp8,
                        const double* __restrict__ losssum,
                        float* __restrict__ out) {
  const int t = threadIdx.x;
  double part = 0.0;
  for (int k = t; k < KC; k += 256) {
    float a4 = 0.f;
    #pragma unroll
    for (int s = 0; s < 8; ++s) a4 += avgp8[s * KC + k];
    double a = (double)a4 / (double)NROWS;
    part += a * log(a + 1e-10);
  }
  __shared__ double sd[256];
  sd[t] = part;
  __syncthreads();
  for (int s = 128; s > 0; s >>= 1) {
    if (t < s) sd[t] += sd[t + s];
    __syncthreads();
  }
  if (t == 0) {
    double H = -sd[0];
    double mse = losssum[0] / (double)((size_t)NROWS * DIM);
    double ccl = 1.25 * mse;
    double sel = -0.1 * H;
    out[OUT_SCAL + 0] = (float)(ccl + sel);
    out[OUT_SCAL + 1] = (float)ccl;
    out[OUT_SCAL + 2] = (float)sel;
  }
}

extern "C" void kernel_launch(void* const* d_in, const int* in_sizes, int n_in,
                              void* d_out, int out_size, void* d_ws, size_t ws_size,
                              hipStream_t stream) {
  const float* z = (const float*)d_in[0];
  const float* cbw = (const float*)d_in[1];
  float* out = (float*)d_out;
  char* ws = (char*)d_ws;
  float* cnorm = (float*)(ws + WS_CNORM);
  float* znorm = (float*)(ws + WS_ZNORM);
  double* losssum = (double*)(ws + WS_LOSS);
  float* avgp8 = (float*)(ws + WS_AVGP8);
  __bf16* frag = (__bf16*)(ws + WS_FRAG);

  hipMemsetAsync(ws + WS_LOSS, 0, 8, stream);
  hipMemsetAsync(ws + WS_AVGP8, 0, 8 * KC * 4, stream);
  k_norms<<<(KC + NROWS) / 256, 256, 0, stream>>>(cbw, z, cnorm, znorm);
  k_frag<<<(KC * 32) / 256, 256, 0, stream>>>(cbw, frag);
  k_main<<<NROWS / BM, 256, 0, stream>>>(z, cbw, cnorm, znorm, frag, out,
                                         avgp8, losssum);
  k_final<<<1, 256, 0, stream>>>(avgp8, losssum, out);
}